// Round 6
// baseline (174.636 us; speedup 1.0000x reference)
//
#include <hip/hip_runtime.h>
#include <math.h>

#define NGRAPH 256
#define HEADS  8
#define DIN    512
#define EPG    256   // edges per graph
#define NEDGE  65536
#define LOG2E 1.44269504088896341f
#define LN2   0.69314718055994531f

typedef short bf16x8 __attribute__((ext_vector_type(8)));
typedef float f32x4 __attribute__((ext_vector_type(4)));

__device__ __forceinline__ float softplusf(float v) {
    if (v > 20.f) return v;
    float t = exp2f(v * LOG2E);
    return LN2 * log2f(1.f + t);
}
__device__ __forceinline__ unsigned short f2bf(float f) {   // RNE f32 -> bf16
    union { float f; unsigned u; } c; c.f = f;
    unsigned r = c.u + 0x7fffu + ((c.u >> 16) & 1u);
    return (unsigned short)(r >> 16);
}
__device__ __forceinline__ float bf2f(unsigned short h) {
    union { float f; unsigned u; } c; c.u = ((unsigned)h) << 16;
    return c.f;
}
// XOR-swizzle for [64][64] bf16 tile (16B-group granularity) — used for Wl.
__device__ __forceinline__ int swz_idx(int row, int t) {
    int g = ((t >> 3) ^ (row ^ (row >> 3))) & 7;
    return (row << 6) | (g << 3) | (t & 7);
}
// XOR-swizzle for [64][32] bf16 tile (16B groups, 4 groups/row) — CB stage chunks.
// b128 reads across 16 rows: (parity, g) spreads rows over 8 slot classes -> <=2-way.
__device__ __forceinline__ int swz32(int row, int t) {
    int g = ((t >> 3) ^ (row & 3) ^ ((row >> 2) & 3)) & 3;
    return row * 32 + g * 8 + (t & 7);
}
// split f32 -> bf16 hi (truncation) + bf16 lo (truncation of residual)
__device__ __forceinline__ void split1(float f, unsigned short& hi, unsigned short& lo) {
    union { float f; unsigned q; } c; c.f = f;
    unsigned hb = c.q & 0xffff0000u;
    hi = (unsigned short)(hb >> 16);
    union { float f; unsigned q; } d; d.q = hb;
    union { float f; unsigned q; } e2; e2.f = f - d.f;
    lo = (unsigned short)(e2.q >> 16);
}

// Stage one 32-col chunk of C and B (f32 global) as split-bf16 swizzled tiles.
// buf layout (ush): Chi=0, Clo=2048, Bhi=4096, Blo=6144 (each [64][32] swizzled).
__device__ __forceinline__ void stage32(int c, unsigned short* buf,
                                        const float* __restrict__ Cm,
                                        const float* __restrict__ Bm,
                                        int b, int tid) {
    #pragma unroll
    for (int i = 0; i < 4; ++i) {
        int rem = ((i & 1) << 8) + tid;      // 0..511
        int row = rem >> 3;
        int col4 = (rem & 7) << 2;
        const float* src = ((i >> 1) ? Bm : Cm) + ((size_t)(b * 64 + row)) * DIN + c * 32 + col4;
        float4 v = *(const float4*)src;
        float a[4] = {v.x, v.y, v.z, v.w};
        unsigned long long hp = 0, lp = 0;
        #pragma unroll
        for (int k = 0; k < 4; ++k) {
            unsigned short h, l;
            split1(a[k], h, l);
            hp |= ((unsigned long long)h) << (16 * k);
            lp |= ((unsigned long long)l) << (16 * k);
        }
        int idx = swz32(row, col4);          // col4&7 in {0,4}: 8B-aligned in group
        unsigned short* t2 = buf + (i >> 1) * 4096;
        *(unsigned long long*)(t2 + idx) = hp;
        *(unsigned long long*)(t2 + 2048 + idx) = lp;
    }
}

// 512 blocks: (graph b = gid&255, half = gid>>8). 256 threads = 4 waves; wave w
// owns head h = half*4+w end-to-end. LDS 53,248 B -> 3 blocks/CU resident.
// CB (head-independent) computed per block (2x/graph; cheap, staged once per block).
__global__ __launch_bounds__(256, 3) void dag_split_v4(
        const float* __restrict__ x,
        const float* __restrict__ Bm,
        const float* __restrict__ Cm,
        const float* __restrict__ dt,
        const float* __restrict__ dt_edge,
        const float* __restrict__ dt_bias,
        const float* __restrict__ Dp,
        const float* __restrict__ dag_masks,
        const int* __restrict__ edge_index,
        float* __restrict__ out) {
    __shared__ __align__(16) unsigned short WS[16384];   // 32KB: stage ping-pong -> Wl[4][4096]
    __shared__ __align__(16) unsigned short CBsh[4096];  // CB[i][t] bf16, 8KB
    __shared__ __align__(16) float Ab8[4][512];          // band [i][8] padded (slot0=0), 8KB
    __shared__ float dts[4][64];
    __shared__ float dtt[4][64];
    __shared__ float dnsh[4][64];
    __shared__ float ecsh[4][64];                        // per-head replica (wave-private)

    const int gid = blockIdx.x;
    const int b = gid & 255;
    const int half = gid >> 8;
    const int tid = threadIdx.x;
    const int w = tid >> 6;
    const int lane = tid & 63;
    const int lm = lane & 15;
    const int quad = lane >> 4;
    const int h = half * 4 + w;          // this wave's head
    const float bias = dt_bias[h];

    // ---- phase 0 (wave-private): node softplus + zero own arrays ----
    {
        float2 dv = *(const float2*)(dt + ((size_t)(b * 64 + lane)) * 16 + h * 2);
        dts[w][lane] = softplusf(dv.x + bias);
        dtt[w][lane] = softplusf(dv.y + bias);
        dnsh[w][lane] = 0.f;
        ecsh[w][lane] = 0.f;
        float4 z = make_float4(0.f, 0.f, 0.f, 0.f);
        *(float4*)(&Ab8[w][lane * 8]) = z;
        *(float4*)(&Ab8[w][lane * 8 + 4]) = z;
    }

    // ---- edge scatter (wave-private; own head, own ec replica) ----
    {
        #pragma unroll
        for (int eo = 0; eo < 4; ++eo) {
            int e = b * EPG + eo * 64 + lane;
            int sl = edge_index[e] & 63;
            int dl = edge_index[NEDGE + e] & 63;
            float mk = dag_masks[e];
            float de = softplusf(dt_edge[(size_t)e * HEADS + h] + bias);
            float dsum = (dts[w][sl] + dtt[w][dl] + de) * 0.57735026918962576451f; // 1/sqrt(3)
            float dexp = exp2f(-dsum * LOG2E);
            atomicAdd(&Ab8[w][dl * 8 + (dl - sl)], dexp * mk);   // dl-sl in [1,7]
            atomicAdd(&dnsh[w][dl], dsum * mk);
            atomicAdd(&ecsh[w][dl], mk);
        }
    }

    // ---- band normalize (wave-private; lane i = row i) ----
    {
        float eci = ecsh[w][lane];
        float4 a03 = *(const float4*)(&Ab8[w][lane * 8]);
        float4 a47 = *(const float4*)(&Ab8[w][lane * 8 + 4]);
        float sc[7];
        #pragma unroll
        for (int s = 0; s < 7; ++s) {
            int src = lane - 1 - s;
            float p = (src >= 0) ? eci * ecsh[w][src] : 1.f;
            sc[s] = fminf(1.f, rsqrtf(p));   // 1/max(1,sqrt(p)); p=0 -> 1
        }
        a03.y *= sc[0]; a03.z *= sc[1]; a03.w *= sc[2];
        a47.x *= sc[3]; a47.y *= sc[4]; a47.z *= sc[5]; a47.w *= sc[6];
        *(float4*)(&Ab8[w][lane * 8]) = a03;
        *(float4*)(&Ab8[w][lane * 8 + 4]) = a47;
    }

    // ---- CB = C·B^T via split-bf16 MFMA; 16 x 32-col chunks, ping-pong staged ----
    // wave w owns CB rows [16w,16w+16); acc[ni] covers cols [16ni,16ni+16)
    {
        f32x4 acc[4];
        #pragma unroll
        for (int ni = 0; ni < 4; ++ni) acc[ni] = (f32x4){0.f, 0.f, 0.f, 0.f};
        stage32(0, WS, Cm, Bm, b, tid);
        for (int c = 0; c < 16; ++c) {
            __syncthreads();
            if (c < 15) stage32(c + 1, WS + ((c + 1) & 1) * 8192, Cm, Bm, b, tid);
            const unsigned short* p = WS + (c & 1) * 8192;
            bf16x8 ah = *(const bf16x8*)(p + swz32(w * 16 + lm, quad * 8));
            bf16x8 al = *(const bf16x8*)(p + 2048 + swz32(w * 16 + lm, quad * 8));
            #pragma unroll
            for (int ni = 0; ni < 4; ++ni) {
                bf16x8 bh = *(const bf16x8*)(p + 4096 + swz32(ni * 16 + lm, quad * 8));
                bf16x8 bl = *(const bf16x8*)(p + 6144 + swz32(ni * 16 + lm, quad * 8));
                acc[ni] = __builtin_amdgcn_mfma_f32_16x16x32_bf16(ah, bh, acc[ni], 0, 0, 0);
                acc[ni] = __builtin_amdgcn_mfma_f32_16x16x32_bf16(ah, bl, acc[ni], 0, 0, 0);
                acc[ni] = __builtin_amdgcn_mfma_f32_16x16x32_bf16(al, bh, acc[ni], 0, 0, 0);
            }
        }
        // C/D layout: col = lane&15, row = quad*4 + r
        #pragma unroll
        for (int ni = 0; ni < 4; ++ni)
            #pragma unroll
            for (int r = 0; r < 4; ++r)
                CBsh[(w * 16 + quad * 4 + r) * 64 + ni * 16 + lm] = f2bf(acc[ni][r]);
    }
    __syncthreads();   // publishes CBsh; stage buffers dead -> WS becomes Wl[4]

    // ---- banded forward solve (wave-private; lane j = column j) ----
    unsigned short* Wlw = WS + w * 4096;
    {
        const int j = lane;
        const float Dh = Dp[h];
        float mwin[7] = {0.f, 0.f, 0.f, 0.f, 0.f, 0.f, 0.f};
        float4 a03 = *(const float4*)(&Ab8[w][0]);
        float4 a47 = *(const float4*)(&Ab8[w][4]);
        float cbv = bf2f(CBsh[j]);
        float dnv = dnsh[w][0];
        #pragma unroll 2
        for (int i = 0; i < 64; ++i) {
            float4 n03, n47;
            float ncb = 0.f, ndn = 0.f;
            if (i < 63) {
                n03 = *(const float4*)(&Ab8[w][(i + 1) * 8]);
                n47 = *(const float4*)(&Ab8[w][(i + 1) * 8 + 4]);
                ncb = bf2f(CBsh[(i + 1) * 64 + j]);
                ndn = dnsh[w][i + 1];
            } else {
                n03 = make_float4(0.f, 0.f, 0.f, 0.f);
                n47 = n03;
            }
            float diag = (j == i) ? 1.f : 0.f;
            float t0 = fmaf(a03.y, mwin[0], fmaf(a03.z, mwin[1], diag));
            float t1 = fmaf(a03.w, mwin[2], fmaf(a47.x, mwin[3], a47.y * mwin[4]));
            float t2 = fmaf(a47.z, mwin[5], a47.w * mwin[6]);
            float mi_ = t0 + (t1 + t2);
            float wv = mi_ * cbv * dnv;
            if (j == i) wv += Dh;
            Wlw[swz_idx(i, j)] = f2bf(wv);   // i uniform -> conflict-free
            #pragma unroll
            for (int s = 6; s > 0; --s) mwin[s] = mwin[s - 1];
            mwin[0] = mi_;
            a03 = n03; a47 = n47;
            cbv = ncb; dnv = ndn;
        }
    }

    // ---- y = W·X: A-frag from Wl (LDS), B-frag DIRECT from global x (no Xt) ----
    // B-frag: lane holds X[t=ks*32+quad*8+j][e=eb*16+lm] -- coalesced 64B/quarter-wave
    {
        const float* xh = x + ((size_t)b * 64) * DIN + h * 64;
        bf16x8 bfr[4][2];
        #pragma unroll
        for (int eb = 0; eb < 4; ++eb)
            #pragma unroll
            for (int ks = 0; ks < 2; ++ks) {
                bf16x8 f;
                #pragma unroll
                for (int jj = 0; jj < 8; ++jj) {
                    float xv = xh[(size_t)(ks * 32 + quad * 8 + jj) * DIN + eb * 16 + lm];
                    f[jj] = (short)f2bf(xv);
                }
                bfr[eb][ks] = f;
            }
        float* og = out + ((size_t)b * 64) * DIN + h * 64;
        #pragma unroll
        for (int m2 = 0; m2 < 4; ++m2) {
            int row0 = m2 * 16 + lm;
            bf16x8 a0 = *(const bf16x8*)(&Wlw[swz_idx(row0, quad * 8)]);
            bf16x8 a1 = *(const bf16x8*)(&Wlw[swz_idx(row0, 32 + quad * 8)]);
            f32x4 acc[4];
            #pragma unroll
            for (int eb = 0; eb < 4; ++eb) {
                f32x4 z = {0.f, 0.f, 0.f, 0.f};
                z = __builtin_amdgcn_mfma_f32_16x16x32_bf16(a0, bfr[eb][0], z, 0, 0, 0);
                z = __builtin_amdgcn_mfma_f32_16x16x32_bf16(a1, bfr[eb][1], z, 0, 0, 0);
                acc[eb] = z;
            }
            #pragma unroll
            for (int r = 0; r < 4; ++r) {
                int row = m2 * 16 + quad * 4 + r;
                #pragma unroll
                for (int eb = 0; eb < 4; ++eb)
                    og[(size_t)row * DIN + eb * 16 + lm] = acc[eb][r];
            }
        }
    }
}

extern "C" void kernel_launch(void* const* d_in, const int* in_sizes, int n_in,
                              void* d_out, int out_size, void* d_ws, size_t ws_size,
                              hipStream_t stream) {
    (void)in_sizes; (void)n_in; (void)out_size; (void)d_ws; (void)ws_size;
    dag_split_v4<<<dim3(512), dim3(256), 0, stream>>>(
        (const float*)d_in[0],   // x
        (const float*)d_in[1],   // B
        (const float*)d_in[2],   // C
        (const float*)d_in[3],   // dt
        (const float*)d_in[4],   // dt_edge
        (const float*)d_in[5],   // dt_bias
        (const float*)d_in[6],   // D
        (const float*)d_in[7],   // dag_masks
        (const int*)d_in[8],     // edge_index
        (float*)d_out);
}